// Round 3
// baseline (2096.034 us; speedup 1.0000x reference)
//
#include <hip/hip_runtime.h>
#include <hip/hip_fp16.h>
#include <stdint.h>

// Problem constants (fixed by the reference file)
#define M_DIM 8192    // B*S = 4*2048
#define K_DIM 4096    // IN_F
#define N_DIM 11008   // OUT_F

// Harness dtype model (derived from round-1/2 forensics):
//   x, scale, bias: fp16 in the reference -> delivered as float32 buffers
//   qweight: int8 in the reference -> delivered as int32 (sniff confirms)
//   output: fp16 in the reference -> float32 buffer
// x values and w values are exactly fp16-representable -> f16 MFMA is exact.

#define BM 128
#define BN 128
#define BK 32
#define TM (M_DIM / BM)   // 64
#define TN (N_DIM / BN)   // 86

typedef _Float16 f16x8 __attribute__((ext_vector_type(8)));  // 8 fp16 = 4 VGPRs
typedef float f32x4 __attribute__((ext_vector_type(4)));     // MFMA 16x16 acc

// Decide whether qweight arrived as int32 (harness-upcast) or raw int8.
// int32 data: 4096 consecutive words all in [-127,127]. Raw int8: a word is
// 4 random bytes -> essentially never passes.
__global__ void sniff_kernel(const int* __restrict__ q, int* __restrict__ flag) {
    __shared__ int s;
    if (threadIdx.x == 0) s = 1;
    __syncthreads();
    int bad = 0;
#pragma unroll
    for (int i = 0; i < 16; ++i) {
        int v = q[threadIdx.x * 16 + i];
        if (v < -127 || v > 127) bad = 1;
    }
    if (bad) s = 0;   // benign race: all writers write 0
    __syncthreads();
    if (threadIdx.x == 0) flag[0] = s;
}

// C[M,N] = A[M,K] * W[N,K]^T; epilogue y = acc*scale[n] + bias[n]. All f32 I/O.
__global__ __launch_bounds__(256)
void w8_gemm_kernel(const float* __restrict__ A,      // f32 (fp16 values) [M,K]
                    const void* __restrict__ Wv,      // int32 or int8 [N,K]
                    const float* __restrict__ scale,  // f32 [N]
                    const float* __restrict__ bias,   // f32 [N]
                    float* __restrict__ C,            // f32 [M,N]
                    const int* __restrict__ flag)
{
    __shared__ __align__(16) _Float16 As[BM * BK];   // 8 KB
    __shared__ __align__(16) _Float16 Bs[BN * BK];   // 8 KB

    const int tid  = threadIdx.x;
    const int wave = tid >> 6;
    const int lane = tid & 63;
    const int quad = lane >> 4;
    const int col  = lane & 15;

    const bool w_is_i32 = (flag[0] != 0);   // wave-uniform branch

    // Swizzle: groups of 8 m-tiles sweep all n-tiles (A strips hot in L2).
    int bid = blockIdx.x;
    const int per_group = 8 * TN;
    int g = bid / per_group;
    int r = bid - g * per_group;
    const int bm = g * 8 + (r & 7);
    const int bn = r >> 3;

    const int m0 = bm * BM;
    const int n0 = bn * BN;
    const int wm = (wave >> 1) * 64;
    const int wn = (wave & 1) * 64;

    f32x4 acc[4][4];
#pragma unroll
    for (int mi = 0; mi < 4; ++mi)
#pragma unroll
        for (int ni = 0; ni < 4; ++ni)
            acc[mi][ni] = (f32x4){0.f, 0.f, 0.f, 0.f};

    for (int k0 = 0; k0 < K_DIM; k0 += BK) {
        // ---- stage A (128x32): f32 global -> fp16 LDS, 512 chunks of 8 ----
#pragma unroll
        for (int i = 0; i < 2; ++i) {
            int idx = i * 256 + tid;
            int row = idx >> 2;      // 4 chunks per row (32 elems)
            int c   = idx & 3;
            const float4* p = (const float4*)(A + (size_t)(m0 + row) * K_DIM + k0 + c * 8);
            float4 v0 = p[0];
            float4 v1 = p[1];
            f16x8 h;
            h[0] = (_Float16)v0.x; h[1] = (_Float16)v0.y;
            h[2] = (_Float16)v0.z; h[3] = (_Float16)v0.w;
            h[4] = (_Float16)v1.x; h[5] = (_Float16)v1.y;
            h[6] = (_Float16)v1.z; h[7] = (_Float16)v1.w;
            *(f16x8*)(As + idx * 8) = h;
        }
        // ---- stage W (128x32): int -> fp16 LDS (exact, |w|<=127) ----
        if (w_is_i32) {
            const int* Wq = (const int*)Wv;
#pragma unroll
            for (int i = 0; i < 2; ++i) {
                int idx = i * 256 + tid;
                int row = idx >> 2;
                int c   = idx & 3;
                const int4* p = (const int4*)(Wq + (size_t)(n0 + row) * K_DIM + k0 + c * 8);
                int4 a = p[0];
                int4 b = p[1];
                f16x8 h;
                h[0] = (_Float16)a.x; h[1] = (_Float16)a.y;
                h[2] = (_Float16)a.z; h[3] = (_Float16)a.w;
                h[4] = (_Float16)b.x; h[5] = (_Float16)b.y;
                h[6] = (_Float16)b.z; h[7] = (_Float16)b.w;
                *(f16x8*)(Bs + idx * 8) = h;
            }
        } else {
            const signed char* W8 = (const signed char*)Wv;
#pragma unroll
            for (int i = 0; i < 2; ++i) {
                int idx = i * 256 + tid;
                int row = idx >> 2;
                int c   = idx & 3;
                const int2* p = (const int2*)(W8 + (size_t)(n0 + row) * K_DIM + k0 + c * 8);
                int2 raw = p[0];
                f16x8 h;
                h[0] = (_Float16)(signed char)(raw.x & 0xff);
                h[1] = (_Float16)(signed char)((raw.x >> 8) & 0xff);
                h[2] = (_Float16)(signed char)((raw.x >> 16) & 0xff);
                h[3] = (_Float16)(signed char)((raw.x >> 24) & 0xff);
                h[4] = (_Float16)(signed char)(raw.y & 0xff);
                h[5] = (_Float16)(signed char)((raw.y >> 8) & 0xff);
                h[6] = (_Float16)(signed char)((raw.y >> 16) & 0xff);
                h[7] = (_Float16)(signed char)((raw.y >> 24) & 0xff);
                *(f16x8*)(Bs + idx * 8) = h;
            }
        }
        __syncthreads();

        // ---- fragments -> 16 MFMAs (A[m=lane&15][k=quad*8+j]) ----
        f16x8 af[4], bfr[4];
#pragma unroll
        for (int mi = 0; mi < 4; ++mi)
            af[mi] = *(const f16x8*)(As + (wm + mi * 16 + col) * BK + quad * 8);
#pragma unroll
        for (int ni = 0; ni < 4; ++ni)
            bfr[ni] = *(const f16x8*)(Bs + (wn + ni * 16 + col) * BK + quad * 8);
#pragma unroll
        for (int mi = 0; mi < 4; ++mi)
#pragma unroll
            for (int ni = 0; ni < 4; ++ni)
                acc[mi][ni] = __builtin_amdgcn_mfma_f32_16x16x32_f16(
                    af[mi], bfr[ni], acc[mi][ni], 0, 0, 0);
        __syncthreads();
    }

    // ---- epilogue: C/D map col=lane&15, row=quad*4+reg (m89-verified) ----
    float scl[4], bs[4];
#pragma unroll
    for (int ni = 0; ni < 4; ++ni) {
        int n = n0 + wn + ni * 16 + col;
        scl[ni] = scale[n];
        bs[ni]  = bias[n];
    }
#pragma unroll
    for (int mi = 0; mi < 4; ++mi) {
#pragma unroll
        for (int rr = 0; rr < 4; ++rr) {
            int m = m0 + wm + mi * 16 + quad * 4 + rr;
            float* cp = C + (size_t)m * N_DIM + n0 + wn + col;
#pragma unroll
            for (int ni = 0; ni < 4; ++ni) {
                cp[ni * 16] = acc[mi][ni][rr] * scl[ni] + bs[ni];
            }
        }
    }
}

extern "C" void kernel_launch(void* const* d_in, const int* in_sizes, int n_in,
                              void* d_out, int out_size, void* d_ws, size_t ws_size,
                              hipStream_t stream) {
    const float* x     = (const float*)d_in[0];   // fp16 values, f32 storage
    const void*  qw    = d_in[1];                 // int32 (or raw int8) [N,K]
    const float* scale = (const float*)d_in[2];
    const float* bias  = (const float*)d_in[3];
    float* out = (float*)d_out;
    int* flag = (int*)d_ws;   // written every launch before being read

    sniff_kernel<<<1, 256, 0, stream>>>((const int*)qw, flag);
    w8_gemm_kernel<<<TM * TN, 256, 0, stream>>>(x, qw, scale, bias, out, flag);
}